// Round 1
// baseline (523.046 us; speedup 1.0000x reference)
//
#include <hip/hip_runtime.h>

typedef float f32x4 __attribute__((ext_vector_type(4)));
typedef __bf16 bf16x8 __attribute__((ext_vector_type(8)));
typedef unsigned int u32x4 __attribute__((ext_vector_type(4)));
typedef unsigned short u16;

#define DEV __device__ __forceinline__

DEV u16 f2bf(float f) {
    unsigned int x = __float_as_uint(f);
    x += 0x7fffu + ((x >> 16) & 1u);   // round-to-nearest-even
    return (u16)(x >> 16);
}
DEV float elu(float x) { return x > 0.f ? x : expm1f(x); }

constexpr float INV_M = 1.f / 16384.f;   // B*N
constexpr float EPSV  = 1e-5f;

// ---------------- one-time conversion kernels ----------------

__global__ void k_cvt_bf16(const float* __restrict__ src, u16* __restrict__ dst) {
    long i = ((long)blockIdx.x * 256 + threadIdx.x) * 8;
    f32x4 a = *(const f32x4*)(src + i);
    f32x4 b = *(const f32x4*)(src + i + 4);
    u32x4 v;
    v[0] = (unsigned)f2bf(a[0]) | ((unsigned)f2bf(a[1]) << 16);
    v[1] = (unsigned)f2bf(a[2]) | ((unsigned)f2bf(a[3]) << 16);
    v[2] = (unsigned)f2bf(b[0]) | ((unsigned)f2bf(b[1]) << 16);
    v[3] = (unsigned)f2bf(b[2]) | ((unsigned)f2bf(b[3]) << 16);
    *(u32x4*)(dst + i) = v;
}

// W_blocks [15][128][128] -> WT bf16 [15][e][d] = W[k][d][e]
__global__ void k_cvt_wt(const float* __restrict__ W, u16* __restrict__ WT) {
    int o = blockIdx.x * 256 + threadIdx.x;     // < 15*128*128
    int k = o >> 14, r = o & 16383, e = r >> 7, d = r & 127;
    WT[o] = f2bf(W[(k << 14) + (d << 7) + e]);
}

// x1 = inputs @ W1 + b1 ; x2 = 0
__global__ void k_init(const float* __restrict__ in, const float* __restrict__ W1,
                       const float* __restrict__ b1, float* __restrict__ x1,
                       float* __restrict__ x2) {
    int gid = blockIdx.x * 256 + threadIdx.x;   // < 16*1024*128
    int d = gid & 127; int row = gid >> 7;
    const float* ip = in + row * 3;
    float v = ip[0]*W1[d] + ip[1]*W1[128+d] + ip[2]*W1[256+d] + b1[d];
    x1[gid] = v; x2[gid] = 0.f;
}

// ---------------- per-iteration kernels ----------------

// per-channel sum/sumsq partials: part[block][2][128]
__global__ void k_stats(const float* __restrict__ x, float* __restrict__ part) {
    int t = threadIdx.x; int d = t & 127, h = t >> 7;
    long r0 = (long)blockIdx.x * 128;
    float sum = 0.f, sq = 0.f;
    const float* p = x + (r0 + h) * 128 + d;
    for (int i = 0; i < 64; ++i) { float v = p[i * 256]; sum += v; sq += v * v; }
    __shared__ float ssum[256], ssq[256];
    ssum[t] = sum; ssq[t] = sq;
    __syncthreads();
    if (t < 128) {
        part[(blockIdx.x * 2 + 0) * 128 + t] = ssum[t] + ssum[t + 128];
        part[(blockIdx.x * 2 + 1) * 128 + t] = ssq[t] + ssq[t + 128];
    }
}

// h = elu(bn(x)) -> hT bf16 [b][d][n]  (tile transpose through LDS)
__global__ void k_bnelu(const float* __restrict__ x, const float* __restrict__ part,
                        const float* __restrict__ gamma, const float* __restrict__ beta,
                        u16* __restrict__ hT) {
    __shared__ float sc[128], sh[128];
    __shared__ float tile[64][129];
    int t = threadIdx.x;
    int R = blockIdx.x * 64;
    int bb = R >> 10, n0 = R & 1023;
    if (t < 128) {
        float sum = 0.f, sq = 0.f;
        for (int i = 0; i < 128; ++i) {
            sum += part[(i * 2) * 128 + t];
            sq  += part[(i * 2 + 1) * 128 + t];
        }
        float mean = sum * INV_M;
        float var  = sq * INV_M - mean * mean;
        float s = rsqrtf(var + EPSV) * gamma[t];
        sc[t] = s; sh[t] = beta[t] - mean * s;
    }
    __syncthreads();
    const float* xb = x + (long)R * 128;
    for (int i = 0; i < 8; ++i) {
        int f = t + 256 * i;
        int row = f >> 5, c = (f & 31) * 4;
        f32x4 v = *(const f32x4*)(xb + row * 128 + c);
        tile[row][c]     = elu(v[0] * sc[c]     + sh[c]);
        tile[row][c + 1] = elu(v[1] * sc[c + 1] + sh[c + 1]);
        tile[row][c + 2] = elu(v[2] * sc[c + 2] + sh[c + 2]);
        tile[row][c + 3] = elu(v[3] * sc[c + 3] + sh[c + 3]);
    }
    __syncthreads();
    int d = t >> 1, seg = t & 1;
    u16* orow = hT + ((long)(bb * 128 + d)) * 1024 + n0 + seg * 32;
    for (int u = 0; u < 4; ++u) {
        int nb = seg * 32 + u * 8;
        u32x4 v;
        v[0] = (unsigned)f2bf(tile[nb+0][d]) | ((unsigned)f2bf(tile[nb+1][d]) << 16);
        v[1] = (unsigned)f2bf(tile[nb+2][d]) | ((unsigned)f2bf(tile[nb+3][d]) << 16);
        v[2] = (unsigned)f2bf(tile[nb+4][d]) | ((unsigned)f2bf(tile[nb+5][d]) << 16);
        v[3] = (unsigned)f2bf(tile[nb+6][d]) | ((unsigned)f2bf(tile[nb+7][d]) << 16);
        *(u32x4*)(orow + u * 8) = v;
    }
}

// fused: agg = L@h  (64x128 tile, K=1024) ; D = agg@W^T ; xio += D + bias
// LDS swizzle everywhere: u16 index ^= (row&7)<<3   (16B-block XOR within 128B)
__global__ __launch_bounds__(256) void k_gemm(
        const u16* __restrict__ Lb, const u16* __restrict__ hT,
        const u16* __restrict__ WT, const float* __restrict__ bias,
        float* __restrict__ xio) {
    extern __shared__ char smem[];
    u16* As = (u16*)smem;               // [2][64][64]
    u16* Bs = (u16*)(smem + 16384);     // [2][128][64]
    u16* Cs = (u16*)(smem + 49152);     // [64][128]
    u16* Ws = (u16*)(smem + 65536);     // [128][128]

    int t = threadIdx.x;
    int bid = blockIdx.x;
    int bb = bid >> 4, n0 = (bid & 15) * 64;
    int l = t & 63, w = t >> 6;
    int wr = w >> 1, wc = w & 1;
    int l16 = l & 15, ld16 = l >> 4;

    // stage W^T (swizzled)
    {
        const u32x4* s = (const u32x4*)WT;
        for (int i = 0; i < 8; ++i) {
            int u = t + 256 * i;            // u32x4 id; 8 u16 each
            int r = u >> 4, c = (u & 15) * 8;
            u32x4 v = s[u];
            *(u32x4*)(Ws + r * 128 + (c ^ ((r & 7) << 3))) = v;
        }
    }

    const u16* gA = Lb + (long)(bb * 1024 + n0) * 1024;
    const u16* gB = hT + (long)bb * 128 * 1024;

    f32x4 acc[2][4] = {};
    u32x4 ar[2], br[4];

    // prologue: tile 0
    for (int i = 0; i < 2; ++i) {
        int u = t + 256 * i; int r = u >> 3, c = (u & 7) * 8;
        ar[i] = *(const u32x4*)(gA + (long)r * 1024 + c);
    }
    for (int i = 0; i < 4; ++i) {
        int u = t + 256 * i; int r = u >> 3, c = (u & 7) * 8;
        br[i] = *(const u32x4*)(gB + (long)r * 1024 + c);
    }
    for (int i = 0; i < 2; ++i) {
        int u = t + 256 * i; int r = u >> 3, c = (u & 7) * 8;
        *(u32x4*)(As + r * 64 + (c ^ ((r & 7) << 3))) = ar[i];
    }
    for (int i = 0; i < 4; ++i) {
        int u = t + 256 * i; int r = u >> 3, c = (u & 7) * 8;
        *(u32x4*)(Bs + r * 64 + (c ^ ((r & 7) << 3))) = br[i];
    }

    int cur = 0;
    for (int kt = 0; kt < 16; ++kt) {
        __syncthreads();
        if (kt < 15) {
            int k0 = (kt + 1) * 64;
            for (int i = 0; i < 2; ++i) {
                int u = t + 256 * i; int r = u >> 3, c = (u & 7) * 8;
                ar[i] = *(const u32x4*)(gA + (long)r * 1024 + k0 + c);
            }
            for (int i = 0; i < 4; ++i) {
                int u = t + 256 * i; int r = u >> 3, c = (u & 7) * 8;
                br[i] = *(const u32x4*)(gB + (long)r * 1024 + k0 + c);
            }
        }
        const u16* Ab = As + cur * 4096;
        const u16* Bb = Bs + cur * 8192;
        for (int ks = 0; ks < 2; ++ks) {
            int kk = ks * 32 + ld16 * 8;
            bf16x8 af[2], bfr[4];
            for (int m = 0; m < 2; ++m) {
                int row = wr * 32 + m * 16 + l16;
                af[m] = *(const bf16x8*)(Ab + row * 64 + (kk ^ ((row & 7) << 3)));
            }
            for (int n = 0; n < 4; ++n) {
                int col = wc * 64 + n * 16 + l16;
                bfr[n] = *(const bf16x8*)(Bb + col * 64 + (kk ^ ((col & 7) << 3)));
            }
            for (int m = 0; m < 2; ++m)
                for (int n = 0; n < 4; ++n)
                    acc[m][n] = __builtin_amdgcn_mfma_f32_16x16x32_bf16(
                        af[m], bfr[n], acc[m][n], 0, 0, 0);
        }
        if (kt < 15) {
            int nb = cur ^ 1;
            u16* Aw = As + nb * 4096; u16* Bw = Bs + nb * 8192;
            for (int i = 0; i < 2; ++i) {
                int u = t + 256 * i; int r = u >> 3, c = (u & 7) * 8;
                *(u32x4*)(Aw + r * 64 + (c ^ ((r & 7) << 3))) = ar[i];
            }
            for (int i = 0; i < 4; ++i) {
                int u = t + 256 * i; int r = u >> 3, c = (u & 7) * 8;
                *(u32x4*)(Bw + r * 64 + (c ^ ((r & 7) << 3))) = br[i];
            }
            cur = nb;
        }
    }

    // phase 2: acc -> Cs (bf16, swizzled)
    __syncthreads();
    for (int m = 0; m < 2; ++m)
        for (int n = 0; n < 4; ++n) {
            int col = wc * 64 + n * 16 + l16;
            for (int j = 0; j < 4; ++j) {
                int row = wr * 32 + m * 16 + ld16 * 4 + j;
                Cs[row * 128 + (col ^ ((row & 7) << 3))] = f2bf(acc[m][n][j]);
            }
        }
    __syncthreads();

    // phase 3: D = C @ W  (B operand = W^T rows)
    f32x4 acc2[2][4] = {};
    for (int ks = 0; ks < 4; ++ks) {
        int kk = ks * 32 + ld16 * 8;
        bf16x8 af[2], bfr[4];
        for (int m = 0; m < 2; ++m) {
            int row = wr * 32 + m * 16 + l16;
            af[m] = *(const bf16x8*)(Cs + row * 128 + (kk ^ ((row & 7) << 3)));
        }
        for (int n = 0; n < 4; ++n) {
            int e = wc * 64 + n * 16 + l16;
            bfr[n] = *(const bf16x8*)(Ws + e * 128 + (kk ^ ((e & 7) << 3)));
        }
        for (int m = 0; m < 2; ++m)
            for (int n = 0; n < 4; ++n)
                acc2[m][n] = __builtin_amdgcn_mfma_f32_16x16x32_bf16(
                    af[m], bfr[n], acc2[m][n], 0, 0, 0);
    }

    // epilogue: x1_new = x2_old + D + bias   (in place over xio)
    float* dst = xio + (long)(bb * 1024 + n0) * 128;
    for (int n = 0; n < 4; ++n) {
        int e = wc * 64 + n * 16 + l16;
        float bv = bias[e];
        for (int m = 0; m < 2; ++m)
            for (int j = 0; j < 4; ++j) {
                int row = wr * 32 + m * 16 + ld16 * 4 + j;
                long idx = (long)row * 128 + e;
                dst[idx] = dst[idx] + acc2[m][n][j] + bv;
            }
    }
}

// ---------------- final kernels ----------------

__global__ void k_stats2(const float* __restrict__ x1, const float* __restrict__ x2,
                         float* __restrict__ part) {
    int t = threadIdx.x; int d = t & 127, h = t >> 7;
    long r0 = (long)blockIdx.x * 128;
    float s1 = 0, q1 = 0, s2 = 0, q2 = 0;
    const float* p1 = x1 + (r0 + h) * 128 + d;
    const float* p2 = x2 + (r0 + h) * 128 + d;
    for (int i = 0; i < 64; ++i) {
        float a = p1[i * 256]; s1 += a; q1 += a * a;
        float b = p2[i * 256]; s2 += b; q2 += b * b;
    }
    __shared__ float sm[4][256];
    sm[0][t] = s1; sm[1][t] = q1; sm[2][t] = s2; sm[3][t] = q2;
    __syncthreads();
    if (t < 128)
        for (int q = 0; q < 4; ++q)
            part[(blockIdx.x * 4 + q) * 128 + t] = sm[q][t] + sm[q][t + 128];
}

__global__ void k_finalpool(const float* __restrict__ x1, const float* __restrict__ x2,
                            const float* __restrict__ part,
                            const float* __restrict__ g1, const float* __restrict__ be1,
                            const float* __restrict__ g2, const float* __restrict__ be2,
                            const float* __restrict__ mask,
                            float* __restrict__ poolP, float* __restrict__ maskP) {
    __shared__ float sc1[128], sh1[128], sc2[128], sh2[128];
    __shared__ float red[8][128];
    __shared__ float msk[64];
    int t = threadIdx.x;
    int R = blockIdx.x * 64, bb = R >> 10, tl = (R & 1023) >> 6;
    if (t < 128) {
        float s1 = 0, q1 = 0, s2 = 0, q2 = 0;
        for (int i = 0; i < 128; ++i) {
            s1 += part[(i * 4 + 0) * 128 + t]; q1 += part[(i * 4 + 1) * 128 + t];
            s2 += part[(i * 4 + 2) * 128 + t]; q2 += part[(i * 4 + 3) * 128 + t];
        }
        float m1 = s1 * INV_M, v1 = q1 * INV_M - m1 * m1;
        float m2 = s2 * INV_M, v2 = q2 * INV_M - m2 * m2;
        float a1 = rsqrtf(v1 + EPSV) * g1[t]; sc1[t] = a1; sh1[t] = be1[t] - m1 * a1;
        float a2 = rsqrtf(v2 + EPSV) * g2[t]; sc2[t] = a2; sh2[t] = be2[t] - m2 * a2;
    }
    if (t >= 128 && t < 192) msk[t - 128] = mask[bb * 1024 + (R & 1023) + (t - 128)];
    __syncthreads();
    const float* xb1 = x1 + (long)R * 128;
    const float* xb2 = x2 + (long)R * 128;
    int row0 = t >> 5, c = (t & 31) * 4;
    f32x4 accv = {0.f, 0.f, 0.f, 0.f};
    for (int i = 0; i < 8; ++i) {
        int row = row0 + 8 * i;
        f32x4 v1 = *(const f32x4*)(xb1 + row * 128 + c);
        f32x4 v2 = *(const f32x4*)(xb2 + row * 128 + c);
        float m = msk[row];
        accv[0] += elu(v1[0]*sc1[c]   + sh1[c]   + v2[0]*sc2[c]   + sh2[c])   * m;
        accv[1] += elu(v1[1]*sc1[c+1] + sh1[c+1] + v2[1]*sc2[c+1] + sh2[c+1]) * m;
        accv[2] += elu(v1[2]*sc1[c+2] + sh1[c+2] + v2[2]*sc2[c+2] + sh2[c+2]) * m;
        accv[3] += elu(v1[3]*sc1[c+3] + sh1[c+3] + v2[3]*sc2[c+3] + sh2[c+3]) * m;
    }
    red[row0][c] = accv[0]; red[row0][c+1] = accv[1];
    red[row0][c+2] = accv[2]; red[row0][c+3] = accv[3];
    __syncthreads();
    if (t < 128) {
        float s = 0;
        for (int g = 0; g < 8; ++g) s += red[g][t];
        poolP[(bb * 16 + tl) * 128 + t] = s;
    }
    if (t == 0) {
        float sm = 0;
        for (int j = 0; j < 64; ++j) sm += msk[j];
        maskP[bb * 16 + tl] = sm;
    }
}

__global__ void k_out(const float* __restrict__ poolP, const float* __restrict__ maskP,
                      const float* __restrict__ W2, const float* __restrict__ b2,
                      float* __restrict__ out) {
    int bb = blockIdx.x, t = threadIdx.x;   // 128 threads
    __shared__ float pooled[128];
    __shared__ float inv;
    float s = 0;
    for (int tl = 0; tl < 16; ++tl) s += poolP[(bb * 16 + tl) * 128 + t];
    pooled[t] = s;
    if (t == 0) {
        float sm = 0;
        for (int tl = 0; tl < 16; ++tl) sm += maskP[bb * 16 + tl];
        inv = 1.f / sm;
    }
    __syncthreads();
    float acc = 0;
    for (int d = 0; d < 128; ++d) acc += pooled[d] * W2[d * 128 + t];
    out[bb * 128 + t] = acc * inv + b2[t];
}

// ---------------- host launcher ----------------

extern "C" void kernel_launch(void* const* d_in, const int* in_sizes, int n_in,
                              void* d_out, int out_size, void* d_ws, size_t ws_size,
                              hipStream_t stream) {
    const float* inputs = (const float*)d_in[0];
    const float* L      = (const float*)d_in[1];
    const float* mask   = (const float*)d_in[2];
    const float* W1     = (const float*)d_in[3];
    const float* b1     = (const float*)d_in[4];
    const float* Wb     = (const float*)d_in[5];
    const float* bblk   = (const float*)d_in[6];
    const float* gb     = (const float*)d_in[7];
    const float* beb    = (const float*)d_in[8];
    const float* g1     = (const float*)d_in[9];
    const float* be1    = (const float*)d_in[10];
    const float* g2     = (const float*)d_in[11];
    const float* be2    = (const float*)d_in[12];
    const float* W2     = (const float*)d_in[13];
    const float* b2     = (const float*)d_in[14];
    float* out = (float*)d_out;

    char* ws = (char*)d_ws;
    u16*   Lb      = (u16*)(ws);                    // 33554432 B
    u16*   WT      = (u16*)(ws + 33554432);         // 491520
    float* xA      = (float*)(ws + 34045952);       // 8388608
    float* xB      = (float*)(ws + 42434560);       // 8388608
    u16*   hT      = (u16*)(ws + 50823168);         // 4194304
    float* statsP  = (float*)(ws + 55017472);       // 131072
    float* stats2P = (float*)(ws + 55148544);       // 262144
    float* poolP   = (float*)(ws + 55410688);       // 131072
    float* maskP   = (float*)(ws + 55541760);       // 1024

    hipLaunchKernelGGL(k_cvt_bf16, dim3(8192), dim3(256), 0, stream, L, Lb);
    hipLaunchKernelGGL(k_cvt_wt,   dim3(960),  dim3(256), 0, stream, Wb, WT);
    hipLaunchKernelGGL(k_init,     dim3(8192), dim3(256), 0, stream, inputs, W1, b1, xA, xB);

    float* pa = xA; float* pb = xB;
    for (int k = 0; k < 15; ++k) {
        hipLaunchKernelGGL(k_stats, dim3(128), dim3(256), 0, stream, pa, statsP);
        hipLaunchKernelGGL(k_bnelu, dim3(256), dim3(256), 0, stream,
                           pa, statsP, gb + k * 128, beb + k * 128, hT);
        hipLaunchKernelGGL(k_gemm, dim3(256), dim3(256), 98304, stream,
                           Lb, hT, WT + k * 16384, bblk + k * 128, pb);
        float* tmp = pa; pa = pb; pb = tmp;
    }
    hipLaunchKernelGGL(k_stats2, dim3(128), dim3(256), 0, stream, pa, pb, stats2P);
    hipLaunchKernelGGL(k_finalpool, dim3(256), dim3(256), 0, stream,
                       pa, pb, stats2P, g1, be1, g2, be2, mask, poolP, maskP);
    hipLaunchKernelGGL(k_out, dim3(16), dim3(128), 0, stream, poolP, maskP, W2, b2, out);
}